// Round 7
// baseline (14000.256 us; speedup 1.0000x reference)
//
#include <hip/hip_runtime.h>
#include <math.h>

#define FH 384
#define KF 193
#define KP 768          // stacked real K' = 2*FH
#define SP 208          // padded complex cols per plane (>=193, mult of 16)
#define SPW 147456      // spatial plane ushorts (384*384)

typedef __attribute__((ext_vector_type(8))) short short8;
typedef __attribute__((ext_vector_type(4))) float f32x4;
typedef unsigned short u16;
typedef unsigned int u32;

static __device__ __forceinline__ float softt(float v, float b) {
    return copysignf(fmaxf(fabsf(v) - b, 0.f), v);
}
static __device__ __forceinline__ u16 bf16_rn(float v) {
    u32 u = __float_as_uint(v);
    return (u16)((u + 0x7FFFu + ((u >> 16) & 1u)) >> 16);
}
static __device__ __forceinline__ float bf2f(u16 h) {
    return __uint_as_float(((u32)h) << 16);
}
// complex load/store on transposed split spectra (uint32 index = col*384 + h)
static __device__ __forceinline__ float2 ldc(const u32* H, const u32* L, size_t i) {
    u32 h = H[i], l = L[i];
    float2 r;
    r.x = __uint_as_float((h & 0xffffu) << 16) + __uint_as_float((l & 0xffffu) << 16);
    r.y = __uint_as_float(h & 0xffff0000u) + __uint_as_float(l & 0xffff0000u);
    return r;
}
static __device__ __forceinline__ void stc(u32* H, u32* L, size_t i, float2 v) {
    u16 hr = bf16_rn(v.x), hi = bf16_rn(v.y);
    u16 lr = bf16_rn(v.x - bf2f(hr)), li = bf16_rn(v.y - bf2f(hi));
    H[i] = (u32)hr | ((u32)hi << 16);
    L[i] = (u32)lr | ((u32)li << 16);
}

// ---------------- tables ----------------
// stacked real DFT matrix (A-operand of col pass): row 2m: [er,-ei]; row 2m+1: [ei,er]
__global__ void init_estack(u16* __restrict__ H, u16* __restrict__ L, int inv)
{
    int idx = blockIdx.x * 256 + threadIdx.x;
    if (idx >= KP * KP) return;
    int gm = idx / KP, kp = idx % KP;
    int m = gm >> 1, comp = gm & 1;
    int t = kp >> 1, ri = kp & 1;
    int mm = (m * t) % FH;
    float th = (float)(6.283185307179586 / FH) * (float)mm;
    float c = cosf(th), s = sinf(th);
    float er, ei;
    if (inv) { er = c * (1.f/FH); ei = s * (1.f/FH); }
    else     { er = c;            ei = -s; }
    float v;
    if (comp == 0) v = (ri == 0) ? er : -ei;
    else           v = (ri == 0) ? ei :  er;
    u16 h = bf16_rn(v);
    H[idx] = h;
    L[idx] = bf16_rn(v - bf2f(h));
}
// r2c B-table transposed: Tt[n][w], n=2k+ri (448 rows, rows>=386 zero)
__global__ void init_tt(u16* __restrict__ H, u16* __restrict__ L)
{
    int idx = blockIdx.x * 256 + threadIdx.x;
    if (idx >= 448 * FH) return;
    int n = idx / FH, w = idx % FH;
    float v = 0.f;
    if (n < 2*KF) {
        int kf = n >> 1, ri = n & 1;
        int m = (w * kf) % FH;
        float th = (float)(6.283185307179586 / FH) * (float)m;
        v = ri ? -sinf(th) : cosf(th);
    }
    u16 h = bf16_rn(v);
    H[idx] = h;
    L[idx] = bf16_rn(v - bf2f(h));
}
// c2r B-table transposed: Ut[x][kp], kp=2k+ri (416 cols, cols>=386 zero)
__global__ void init_ut(u16* __restrict__ H, u16* __restrict__ L)
{
    int idx = blockIdx.x * 256 + threadIdx.x;
    if (idx >= FH * 416) return;
    int x = idx / 416, kp = idx % 416;
    float v = 0.f;
    if (kp < 2*KF) {
        int k = kp >> 1, ri = kp & 1;
        float ck = (k == 0 || k == FH/2) ? (1.f/FH) : (2.f/FH);
        int m = (k * x) % FH;
        float th = (float)(6.283185307179586 / FH) * (float)m;
        v = ri ? -ck*sinf(th) : ck*cosf(th);
    }
    u16 h = bf16_rn(v);
    H[idx] = h;
    L[idx] = bf16_rn(v - bf2f(h));
}

__global__ void w0c_kernel(const float* __restrict__ w0, float* __restrict__ w0c) {
    int t = threadIdx.x;
    if (t < 48) {
        float m = 0.f;
        for (int d = 0; d < 9; ++d) m += w0[t*9+d];
        m *= (1.f/9.f);
        for (int d = 0; d < 9; ++d) w0c[t*9+d] = w0[t*9+d] - m;
    }
}

// ---------------- 3x3 conv (XLA cross-correlation, SAME) ----------------
__global__ __launch_bounds__(256) void conv3x3_kernel(
    const float* __restrict__ inp0, const float* __restrict__ w,
    float* __restrict__ outp0, int Cin, int flip,
    size_t inImgStride, size_t outImgStride)
{
    const float* inp  = inp0  + (size_t)blockIdx.z * inImgStride;
    float*       outp = outp0 + (size_t)blockIdx.z * outImgStride;
    __shared__ float tile[18][19];
    __shared__ float wl[16*16*9];
    int x0 = blockIdx.x * 16, y0 = blockIdx.y * 16;
    int t = threadIdx.x;
    int tx = t & 15, ty = t >> 4;
    int nw = 16 * Cin * 9;
    for (int i = t; i < nw; i += 256) {
        int d = i % 9;
        wl[i] = flip ? w[i + 8 - 2*d] : w[i];
    }
    float acc[16];
#pragma unroll
    for (int co = 0; co < 16; ++co) acc[co] = 0.f;
    for (int ci = 0; ci < Cin; ++ci) {
        __syncthreads();
        for (int i = t; i < 18*18; i += 256) {
            int yy = i / 18, xx = i % 18;
            int gy = y0 - 1 + yy, gx = x0 - 1 + xx;
            float v = 0.f;
            if (gy >= 0 && gy < 256 && gx >= 0 && gx < 256)
                v = inp[((size_t)ci*256 + gy)*256 + gx];
            tile[yy][xx] = v;
        }
        __syncthreads();
        float v[9];
#pragma unroll
        for (int dy = 0; dy < 3; dy++)
#pragma unroll
            for (int dx = 0; dx < 3; dx++) v[dy*3+dx] = tile[ty+dy][tx+dx];
#pragma unroll
        for (int co = 0; co < 16; co++) {
            const float* wp = &wl[(co*Cin+ci)*9];
            acc[co] += v[0]*wp[0]+v[1]*wp[1]+v[2]*wp[2]
                     + v[3]*wp[3]+v[4]*wp[4]+v[5]*wp[5]
                     + v[6]*wp[6]+v[7]*wp[7]+v[8]*wp[8];
        }
    }
#pragma unroll
    for (int co = 0; co < 16; co++)
        outp[((size_t)co*256 + (y0+ty))*256 + (x0+tx)] = acc[co];
}

// ---------------- spatial split kernels (fp32 -> padded bf16 hi/lo planes) ----------------
// layout: H32[plane*73728 + y*192 + x2], two x per uint32
__global__ void zinit_split(const float* __restrict__ fy9, const float* __restrict__ b0,
                            u32* __restrict__ H, u32* __restrict__ L, int total)
{
    int idx = blockIdx.x*256 + threadIdx.x;
    if (idx >= total) return;
    int x2 = idx % 192; int r = idx / 192; int y = r % FH; int plane = r / FH;
    float b = b0[plane & 15];
    u32 hp = 0, lp = 0;
#pragma unroll
    for (int d = 0; d < 2; ++d) {
        int x = x2*2 + d;
        int Y = y + 22; if (Y >= FH) Y -= FH;
        int X = x + 22; if (X >= FH) X -= FH;
        int yy = Y - 44, xx = X - 44;
        float v = 0.f;
        if (yy >= 0 && yy < 256 && xx >= 0 && xx < 256)
            v = fy9[((size_t)plane*256 + yy)*256 + xx];
        v = softt(v, b);
        u16 h = bf16_rn(v), l = bf16_rn(v - bf2f(h));
        hp |= ((u32)h) << (16*d); lp |= ((u32)l) << (16*d);
    }
    H[idx] = hp; L[idx] = lp;
}

__global__ void split_pad(const float* __restrict__ src, int inH, int inW, int offY, int offX,
                          const float* __restrict__ thr,
                          u32* __restrict__ H, u32* __restrict__ L, int total)
{
    int idx = blockIdx.x*256 + threadIdx.x;
    if (idx >= total) return;
    int x2 = idx % 192; int r = idx / 192; int y = r % FH; int plane = r / FH;
    float b = thr ? thr[plane & 15] : 0.f;
    int yy = y - offY;
    u32 hp = 0, lp = 0;
#pragma unroll
    for (int d = 0; d < 2; ++d) {
        int xx = x2*2 + d - offX;
        float v = 0.f;
        if (yy >= 0 && yy < inH && xx >= 0 && xx < inW)
            v = src[((size_t)plane*inH + yy)*inW + xx];
        if (thr) v = softt(v, b);
        u16 h = bf16_rn(v), l = bf16_rn(v - bf2f(h));
        hp |= ((u32)h) << (16*d); lp |= ((u32)l) << (16*d);
    }
    H[idx] = hp; L[idx] = lp;
}

// ---------------- MFMA row pass R2C (no LDS): spatial split planes -> transposed spectrum ---
// grid (7, 3, B); out S[col= plane*208+k][2y+comp]
__global__ __launch_bounds__(256) void r2c_mfma(
    const u16* __restrict__ Hs, const u16* __restrict__ Ls, int ktlo, int kthi,
    const u16* __restrict__ TtH, const u16* __restrict__ TtL,
    u16* __restrict__ outH, u16* __restrict__ outL)
{
    int col0 = blockIdx.x * 64;
    int y0   = blockIdx.y * 128;
    int plane = blockIdx.z;
    int tid = threadIdx.x;
    int wave = tid >> 6, lane = tid & 63;
    int lm = lane & 15, lq = lane >> 4;
    f32x4 acc[2][4];
#pragma unroll
    for (int mi = 0; mi < 2; ++mi)
#pragma unroll
        for (int nj = 0; nj < 4; ++nj) acc[mi][nj] = (f32x4){0.f,0.f,0.f,0.f};
    const u16* hp = Hs + (size_t)plane*SPW;
    const u16* lp = Ls + (size_t)plane*SPW;
    for (int kt = ktlo; kt < kthi; kt += 32) {
        short8 Ah[2], Al[2];
#pragma unroll
        for (int mi = 0; mi < 2; ++mi) {
            size_t off = (size_t)(y0 + (wave*2+mi)*16 + lm)*FH + kt + lq*8;
            Ah[mi] = *(const short8*)(hp + off);
            Al[mi] = *(const short8*)(lp + off);
        }
#pragma unroll
        for (int nj = 0; nj < 4; ++nj) {
            size_t toff = (size_t)(col0 + nj*16 + lm)*FH + kt + lq*8;
            short8 Bh = *(const short8*)(TtH + toff);
            short8 Bl = *(const short8*)(TtL + toff);
#pragma unroll
            for (int mi = 0; mi < 2; ++mi) {
                acc[mi][nj] = __builtin_amdgcn_mfma_f32_16x16x32_bf16(Ah[mi], Bh, acc[mi][nj], 0, 0, 0);
                acc[mi][nj] = __builtin_amdgcn_mfma_f32_16x16x32_bf16(Ah[mi], Bl, acc[mi][nj], 0, 0, 0);
                acc[mi][nj] = __builtin_amdgcn_mfma_f32_16x16x32_bf16(Al[mi], Bh, acc[mi][nj], 0, 0, 0);
            }
        }
    }
    // epilogue: pair re/im via shfl_xor(1), 16B packed stores (even lanes)
#pragma unroll
    for (int mi = 0; mi < 2; ++mi) {
#pragma unroll
        for (int nj = 0; nj < 4; ++nj) {
            int n = col0 + nj*16 + lm;
            int k = n >> 1;
            u16 h[4], l[4];
#pragma unroll
            for (int rr = 0; rr < 4; ++rr) {
                float v = acc[mi][nj][rr];
                h[rr] = bf16_rn(v);
                l[rr] = bf16_rn(v - bf2f(h[rr]));
            }
            u32 hx = (u32)h[0] | ((u32)h[1]<<16), hy = (u32)h[2] | ((u32)h[3]<<16);
            u32 lx = (u32)l[0] | ((u32)l[1]<<16), ly = (u32)l[2] | ((u32)l[3]<<16);
            u32 phx = __shfl_xor((int)hx, 1), phy = __shfl_xor((int)hy, 1);
            u32 plx = __shfl_xor((int)lx, 1), ply = __shfl_xor((int)ly, 1);
            if (((lm & 1) == 0) && k < SP) {
                int ybase = y0 + (wave*2+mi)*16 + lq*4;
                uint4 hv, lv;
                hv.x = (hx & 0xffffu) | (phx << 16);
                hv.y = (hx >> 16)     | (phx & 0xffff0000u);
                hv.z = (hy & 0xffffu) | (phy << 16);
                hv.w = (hy >> 16)     | (phy & 0xffff0000u);
                lv.x = (lx & 0xffffu) | (plx << 16);
                lv.y = (lx >> 16)     | (plx & 0xffff0000u);
                lv.z = (ly & 0xffffu) | (ply << 16);
                lv.w = (ly >> 16)     | (ply & 0xffff0000u);
                size_t dst = ((size_t)plane*SP + k)*KP + 2*ybase;
                *(uint4*)(outH + dst) = hv;
                *(uint4*)(outL + dst) = lv;
            }
        }
    }
}

// ---------------- MFMA col pass (no LDS): C = E·B, transposed spectra in & out ------------
// grid ((N+63)/64, 6)
__global__ __launch_bounds__(256) void zg_mfma(
    const u16* __restrict__ EH, const u16* __restrict__ EL,
    const u16* __restrict__ SH, const u16* __restrict__ SL,
    u16* __restrict__ outH, u16* __restrict__ outL, int N)
{
    int col0 = blockIdx.x * 64;
    int row0 = blockIdx.y * 128;
    int tid = threadIdx.x;
    int wave = tid >> 6, lane = tid & 63;
    int lm = lane & 15, lq = lane >> 4;
    f32x4 acc[2][4];
#pragma unroll
    for (int mi = 0; mi < 2; ++mi)
#pragma unroll
        for (int nj = 0; nj < 4; ++nj) acc[mi][nj] = (f32x4){0.f,0.f,0.f,0.f};
    int arow = row0 + wave*32 + lm;
    for (int kt = 0; kt < KP; kt += 32) {
        short8 Ah[2], Al[2];
#pragma unroll
        for (int mi = 0; mi < 2; ++mi) {
            size_t aoff = (size_t)(arow + mi*16)*KP + kt + lq*8;
            Ah[mi] = *(const short8*)(EH + aoff);
            Al[mi] = *(const short8*)(EL + aoff);
        }
#pragma unroll
        for (int nj = 0; nj < 4; ++nj) {
            if (col0 + nj*16 >= N) continue;
            size_t boff = (size_t)(col0 + nj*16 + lm)*KP + kt + lq*8;
            short8 Bh = *(const short8*)(SH + boff);
            short8 Bl = *(const short8*)(SL + boff);
#pragma unroll
            for (int mi = 0; mi < 2; ++mi) {
                acc[mi][nj] = __builtin_amdgcn_mfma_f32_16x16x32_bf16(Ah[mi], Bh, acc[mi][nj], 0, 0, 0);
                acc[mi][nj] = __builtin_amdgcn_mfma_f32_16x16x32_bf16(Ah[mi], Bl, acc[mi][nj], 0, 0, 0);
                acc[mi][nj] = __builtin_amdgcn_mfma_f32_16x16x32_bf16(Al[mi], Bh, acc[mi][nj], 0, 0, 0);
            }
        }
    }
#pragma unroll
    for (int mi = 0; mi < 2; ++mi) {
#pragma unroll
        for (int nj = 0; nj < 4; ++nj) {
            if (col0 + nj*16 >= N) continue;
            int col = col0 + nj*16 + lm;
            int r0 = row0 + wave*32 + mi*16 + lq*4;
            u16 h[4], l[4];
#pragma unroll
            for (int rr = 0; rr < 4; ++rr) {
                float v = acc[mi][nj][rr];
                h[rr] = bf16_rn(v);
                l[rr] = bf16_rn(v - bf2f(h[rr]));
            }
            uint2 hv, lv;
            hv.x = (u32)h[0] | ((u32)h[1]<<16); hv.y = (u32)h[2] | ((u32)h[3]<<16);
            lv.x = (u32)l[0] | ((u32)l[1]<<16); lv.y = (u32)l[2] | ((u32)l[3]<<16);
            size_t dst = (size_t)col*KP + r0;
            *(uint2*)(outH + dst) = hv;
            *(uint2*)(outL + dst) = lv;
        }
    }
}

// ---------------- MFMA row pass C2R (no LDS): transposed spectrum -> spatial fp32 ----------
// grid (6, 3, B); optional fused softt+split side-output
__global__ __launch_bounds__(256) void c2r_mfma(
    const u32* __restrict__ SH32, const u32* __restrict__ SL32,
    const u16* __restrict__ UtH, const u16* __restrict__ UtL,
    float* __restrict__ outp, const float* __restrict__ thr,
    u16* __restrict__ spH, u16* __restrict__ spL)
{
    int col0 = blockIdx.x * 64;
    int y0   = blockIdx.y * 128;
    int plane = blockIdx.z;
    int tid = threadIdx.x;
    int wave = tid >> 6, lane = tid & 63;
    int lm = lane & 15, lq = lane >> 4;
    f32x4 acc[2][4];
#pragma unroll
    for (int mi = 0; mi < 2; ++mi)
#pragma unroll
        for (int nj = 0; nj < 4; ++nj) acc[mi][nj] = (f32x4){0.f,0.f,0.f,0.f};
    for (int kt = 0; kt < 2*SP; kt += 32) {
        int k0 = (kt + lq*8) >> 1;
        union { short8 s; u32 u[4]; } ah[2], al[2];
#pragma unroll
        for (int mi = 0; mi < 2; ++mi) {
            int ym = y0 + (wave*2+mi)*16 + lm;
            size_t cb = (size_t)plane*SP + k0;
#pragma unroll
            for (int j = 0; j < 4; ++j) {
                ah[mi].u[j] = SH32[(cb + j)*FH + ym];
                al[mi].u[j] = SL32[(cb + j)*FH + ym];
            }
        }
#pragma unroll
        for (int nj = 0; nj < 4; ++nj) {
            size_t toff = (size_t)(col0 + nj*16 + lm)*416 + kt + lq*8;
            short8 Bh = *(const short8*)(UtH + toff);
            short8 Bl = *(const short8*)(UtL + toff);
#pragma unroll
            for (int mi = 0; mi < 2; ++mi) {
                acc[mi][nj] = __builtin_amdgcn_mfma_f32_16x16x32_bf16(ah[mi].s, Bh, acc[mi][nj], 0, 0, 0);
                acc[mi][nj] = __builtin_amdgcn_mfma_f32_16x16x32_bf16(ah[mi].s, Bl, acc[mi][nj], 0, 0, 0);
                acc[mi][nj] = __builtin_amdgcn_mfma_f32_16x16x32_bf16(al[mi].s, Bh, acc[mi][nj], 0, 0, 0);
            }
        }
    }
    float bthr = thr ? thr[plane & 15] : 0.f;
#pragma unroll
    for (int mi = 0; mi < 2; ++mi) {
#pragma unroll
        for (int nj = 0; nj < 4; ++nj) {
            int x = col0 + nj*16 + lm;
#pragma unroll
            for (int rr = 0; rr < 4; ++rr) {
                int y = y0 + (wave*2+mi)*16 + lq*4 + rr;
                float v = acc[mi][nj][rr];
                outp[((size_t)plane*FH + y)*FH + x] = v;
                if (spH) {
                    float s = softt(v, bthr);
                    u16 h = bf16_rn(s), l = bf16_rn(s - bf2f(h));
                    size_t d = (size_t)plane*SPW + (size_t)y*FH + x;
                    spH[d] = h; spL[d] = l;
                }
            }
        }
    }
}

// ---------------- elementwise frequency-domain updates (transposed split spectra) ----------
__global__ void fg_kernel(const u32* __restrict__ FfyH, const u32* __restrict__ FfyL,
                          u32* __restrict__ FzH, u32* __restrict__ FzL,
                          const u32* __restrict__ FkH, const u32* __restrict__ FkL,
                          const float* __restrict__ zetas, int L, int total)
{
    int idx = blockIdx.x*256 + threadIdx.x;
    if (idx >= total) return;
    int h = idx % FH; int r = idx / FH;       // r = col = plane*SP + k
    int k = r % SP; int plane = r / SP;
    int c = plane & 15; int img = plane >> 4;
    float zeta = 10.f * zetas[L*16 + c];
    size_t sidx = (size_t)r*FH + h;
    size_t fidx = ((size_t)img*SP + k)*FH + h;
    float2 fk = ldc(FkH, FkL, fidx);
    float2 fy = ldc(FfyH, FfyL, sidx);
    float2 fz = ldc(FzH, FzL, sidx);
    float nx = zeta*(fk.x*fy.x + fk.y*fy.y) + fz.x;
    float ny = zeta*(fk.x*fy.y - fk.y*fy.x) + fz.y;
    float den = zeta*(fk.x*fk.x + fk.y*fk.y) + 1.f + 1e-8f;
    float inv = 1.f/den;
    float2 o; o.x = nx*inv; o.y = ny*inv;
    stc(FzH, FzL, sidx, o);
}

__global__ void knum_kernel(const u32* __restrict__ FzH, const u32* __restrict__ FzL,
                            const u32* __restrict__ FfyH, const u32* __restrict__ FfyL,
                            const u32* __restrict__ FkH, const u32* __restrict__ FkL,
                            const float* __restrict__ kprox, int L, int total,
                            u32* __restrict__ outH, u32* __restrict__ outL)
{
    int idx = blockIdx.x*256 + threadIdx.x;
    if (idx >= total) return;
    int h = idx % FH; int r = idx / FH;       // r = img*SP + k
    int k = r % SP; int img = r / SP;
    float zk = kprox[L];
    float s1x = 0.f, s1y = 0.f, s2 = 0.f;
    for (int c = 0; c < 16; ++c) {
        size_t si = ((size_t)(img*16 + c)*SP + k)*FH + h;
        float2 fz = ldc(FzH, FzL, si);
        float2 fy = ldc(FfyH, FfyL, si);
        s1x += fz.x*fy.x + fz.y*fy.y;
        s1y += fz.x*fy.y - fz.y*fy.x;
        s2  += fz.x*fz.x + fz.y*fz.y;
    }
    size_t fi = (size_t)r*FH + h;
    float2 fk = ldc(FkH, FkL, fi);
    float nx = zk*s1x + fk.x, ny = zk*s1y + fk.y;
    float den = zk*s2 + 1.f + 1e-8f;
    float inv = 1.f/den;
    float2 o; o.x = nx*inv; o.y = ny*inv;
    stc(outH, outL, fi, o);
}

// ---------------- kernel (blur-kernel) update (fp32 spatial) ----------------
__device__ __forceinline__ void lse_comb(float& m, float& s, float m2, float s2)
{
    if (m2 > m) { s = s * expf(m - m2) + s2; m = m2; }
    else        { s = s + s2 * expf(m2 - m); }
}

__global__ __launch_bounds__(256) void lse_part_kernel(const float* __restrict__ kraw0,
                                                       float2* __restrict__ parts)
{
    int img = blockIdx.y;
    const float* kraw = kraw0 + (size_t)img*FH*FH;
    int b = blockIdx.x, t = threadIdx.x;
    float m = -1e30f, s = 0.f;
    for (int i = b*256 + t; i < FH*FH; i += 64*256) {
        float v = 100.f * kraw[i];
        lse_comb(m, s, v, 1.f);
    }
    __shared__ float sm[256], ss[256];
    sm[t] = m; ss[t] = s;
    __syncthreads();
    for (int st = 128; st > 0; st >>= 1) {
        if (t < st) {
            float mm = sm[t], sc = ss[t];
            lse_comb(mm, sc, sm[t+st], ss[t+st]);
            sm[t] = mm; ss[t] = sc;
        }
        __syncthreads();
    }
    if (t == 0) { float2 o; o.x = sm[0]; o.y = ss[0]; parts[img*64 + b] = o; }
}

__global__ void lse_final_kernel(const float2* __restrict__ parts, float* __restrict__ kmaxB)
{
    int img = blockIdx.x;
    int t = threadIdx.x;
    __shared__ float sm[64], ss[64];
    float2 p = parts[img*64 + t];
    sm[t] = p.x; ss[t] = p.y;
    __syncthreads();
    for (int st = 32; st > 0; st >>= 1) {
        if (t < st) {
            float mm = sm[t], sc = ss[t];
            lse_comb(mm, sc, sm[t+st], ss[t+st]);
            sm[t] = mm; ss[t] = sc;
        }
        __syncthreads();
    }
    if (t == 0) kmaxB[img] = (sm[0] + logf(ss[0])) * 0.01f;
}

__global__ void zero_kernel(float* __restrict__ p, int n)
{
    int i = blockIdx.x*256 + threadIdx.x;
    if (i < n) p[i] = 0.f;
}

__global__ void kdelta_kernel(float* __restrict__ kful, int G)
{
    int t = threadIdx.x;
    if (t < G) kful[(size_t)t*FH*FH + 22*FH + 22] = 1.f;
}

__global__ __launch_bounds__(256) void knew_kernel(const float* __restrict__ kraw0,
    const float* __restrict__ kmax, const float* __restrict__ kb, int L,
    float* __restrict__ kful0)
{
    int img = blockIdx.x;
    const float* kraw = kraw0 + (size_t)img*FH*FH;
    float*       kful = kful0 + (size_t)img*FH*FH;
    int t = threadIdx.x;
    float thr = 0.01f * kb[L] * kmax[img];
    float vs[8]; float loc = 0.f;
#pragma unroll
    for (int ii = 0; ii < 8; ++ii) {
        int i = t + ii*256;
        float v = 0.f;
        if (i < 45*45) {
            int y = i/45, x = i - y*45;
            v = fmaxf(kraw[y*FH + x] - thr, 0.f);
        }
        vs[ii] = v; loc += v;
    }
    __shared__ float sr[256];
    sr[t] = loc; __syncthreads();
    for (int st = 128; st > 0; st >>= 1) { if (t < st) sr[t] += sr[t+st]; __syncthreads(); }
    float den = sr[0] + 1e-8f;
#pragma unroll
    for (int ii = 0; ii < 8; ++ii) {
        int i = t + ii*256;
        if (i < 45*45) {
            int y = i/45, x = i - y*45;
            float v = vs[ii] + ((y == 22 && x == 22) ? 1e-8f : 0.f);
            kful[y*FH + x] = v / den;
        }
    }
}

// ---------------- Fw0 (direct 9-term DFT, inline twiddles) ----------------
__global__ void fw0_kernel(const float* __restrict__ w0c, float2* __restrict__ Fw0)
{
    int idx = blockIdx.x*256 + threadIdx.x;
    if (idx >= 48*FH*KF) return;
    int k = idx % KF; int r = idx / KF;
    int c = r & 15; int r2 = r >> 4;
    int ci = r2 % 3; int h = r2 / 3;
    const float w2pi = (float)(6.283185307179586 / FH);
    float accx = 0.f, accy = 0.f;
#pragma unroll
    for (int ky = 0; ky < 3; ++ky) {
        int a1 = ky - 1; if (a1 < 0) a1 += FH;
        int m1 = (h * a1) % FH;
        float e1x = cosf(w2pi*m1), e1y = -sinf(w2pi*m1);
#pragma unroll
        for (int kx = 0; kx < 3; ++kx) {
            int a2 = kx - 1; if (a2 < 0) a2 += FH;
            int m2 = (k * a2) % FH;
            float e2x = cosf(w2pi*m2), e2y = -sinf(w2pi*m2);
            float wv = w0c[((c*3 + ci)*3 + ky)*3 + kx];
            accx += wv*(e1x*e2x - e1y*e2y);
            accy += wv*(e1x*e2y + e1y*e2x);
        }
    }
    float2 o; o.x = accx; o.y = accy;
    Fw0[idx] = o;
}

// ---------------- final per-bin 3x3 Hermitian Wiener solve ----------------
__global__ void wiener_kernel(const u32* __restrict__ FkH, const u32* __restrict__ FkL,
    const u32* __restrict__ FyH, const u32* __restrict__ FyL,
    const float2* __restrict__ Fw0,
    const u32* __restrict__ FgH, const u32* __restrict__ FgL,
    const float* __restrict__ eta, int total,
    u32* __restrict__ FxH, u32* __restrict__ FxL)
{
    int idx = blockIdx.x*256 + threadIdx.x;
    if (idx >= total) return;
    int h = idx % FH; int r = idx / FH;      // r = img*SP + k
    int k = r % SP; int img = r / SP;
    float2 zo; zo.x = 0.f; zo.y = 0.f;
    if (k >= KF) {
#pragma unroll
        for (int ch = 0; ch < 3; ++ch)
            stc(FxH, FxL, ((size_t)(img*3+ch)*SP + k)*FH + h, zo);
        return;
    }
    float2 fk = ldc(FkH, FkL, (size_t)r*FH + h);
    float fksq = fk.x*fk.x + fk.y*fk.y;
    float2 fyr = ldc(FyH, FyL, ((size_t)(img*3+0)*SP + k)*FH + h);
    float2 fyg = ldc(FyH, FyL, ((size_t)(img*3+1)*SP + k)*FH + h);
    float2 fyb = ldc(FyH, FyL, ((size_t)(img*3+2)*SP + k)*FH + h);
    float Crr = fksq, Cgg = fksq, Cbb = fksq;
    float2 Crg, Crb, Cgb;
    Crg.x = Crg.y = Crb.x = Crb.y = Cgb.x = Cgb.y = 0.f;
    float2 Br, Bg, Bb;
    Br.x = fk.x*fyr.x + fk.y*fyr.y; Br.y = fk.x*fyr.y - fk.y*fyr.x;
    Bg.x = fk.x*fyg.x + fk.y*fyg.y; Bg.y = fk.x*fyg.y - fk.y*fyg.x;
    Bb.x = fk.x*fyb.x + fk.y*fyb.y; Bb.y = fk.x*fyb.y - fk.y*fyb.x;
    for (int c = 0; c < 16; ++c) {
        float es = 10.f * eta[c];
        float2 wr = Fw0[((size_t)h*48 +  0 + c)*KF + k];
        float2 wg = Fw0[((size_t)h*48 + 16 + c)*KF + k];
        float2 wb = Fw0[((size_t)h*48 + 32 + c)*KF + k];
        float2 g  = ldc(FgH, FgL, ((size_t)(img*16+c)*SP + k)*FH + h);
        Crr += es*(wr.x*wr.x + wr.y*wr.y);
        Cgg += es*(wg.x*wg.x + wg.y*wg.y);
        Cbb += es*(wb.x*wb.x + wb.y*wb.y);
        Crg.x += es*(wr.x*wg.x + wr.y*wg.y); Crg.y += es*(wr.x*wg.y - wr.y*wg.x);
        Crb.x += es*(wr.x*wb.x + wr.y*wb.y); Crb.y += es*(wr.x*wb.y - wr.y*wb.x);
        Cgb.x += es*(wg.x*wb.x + wg.y*wb.y); Cgb.y += es*(wg.x*wb.y - wg.y*wb.x);
        Br.x += es*(wr.x*g.x + wr.y*g.y); Br.y += es*(wr.x*g.y - wr.y*g.x);
        Bg.x += es*(wg.x*g.x + wg.y*g.y); Bg.y += es*(wg.x*g.y - wg.y*g.x);
        Bb.x += es*(wb.x*g.x + wb.y*g.y); Bb.y += es*(wb.x*g.y - wb.y*g.x);
    }
    float Crg_sq = Crg.x*Crg.x + Crg.y*Crg.y;
    float Crb_sq = Crb.x*Crb.x + Crb.y*Crb.y;
    float Cgb_sq = Cgb.x*Cgb.x + Cgb.y*Cgb.y;
    float Irr = Cgg*Cbb - Cgb_sq;
    float Igg = Crr*Cbb - Crb_sq;
    float Ibb = Crr*Cgg - Crg_sq;
    float2 Irg, Irb, Igb;
    Irg.x = (Cgb.x*Crb.x + Cgb.y*Crb.y) - Cbb*Crg.x;
    Irg.y = (Cgb.x*Crb.y - Cgb.y*Crb.x) - Cbb*Crg.y;
    Irb.x = (Crg.x*Cgb.x - Crg.y*Cgb.y) - Cgg*Crb.x;
    Irb.y = (Crg.x*Cgb.y + Crg.y*Cgb.x) - Cgg*Crb.y;
    Igb.x = (Crg.x*Crb.x + Crg.y*Crb.y) - Crr*Cgb.x;
    Igb.y = (Crg.x*Crb.y - Crg.y*Crb.x) - Crr*Cgb.y;
    float tx_ = Crg.x*Cgb.x - Crg.y*Cgb.y;
    float ty_ = Crg.x*Cgb.y + Crg.y*Cgb.x;
    float den = Crr*Irr - Cgg*Crb_sq - Cbb*Crg_sq + 2.f*(tx_*Crb.x + ty_*Crb.y) + 1e-8f;
    float inv = 1.f/den;
    float2 o;
    o.x = (Irr*Br.x + (Irg.x*Bg.x - Irg.y*Bg.y) + (Irb.x*Bb.x - Irb.y*Bb.y))*inv;
    o.y = (Irr*Br.y + (Irg.x*Bg.y + Irg.y*Bg.x) + (Irb.x*Bb.y + Irb.y*Bb.x))*inv;
    stc(FxH, FxL, ((size_t)(img*3+0)*SP + k)*FH + h, o);
    o.x = ((Irg.x*Br.x + Irg.y*Br.y) + Igg*Bg.x + (Igb.x*Bb.x - Igb.y*Bb.y))*inv;
    o.y = ((Irg.x*Br.y - Irg.y*Br.x) + Igg*Bg.y + (Igb.x*Bb.y + Igb.y*Bb.x))*inv;
    stc(FxH, FxL, ((size_t)(img*3+1)*SP + k)*FH + h, o);
    o.x = ((Irb.x*Br.x + Irb.y*Br.y) + (Igb.x*Bg.x + Igb.y*Bg.y) + Ibb*Bb.x)*inv;
    o.y = ((Irb.x*Br.y - Irb.y*Br.x) + (Igb.x*Bg.y - Igb.y*Bg.x) + Ibb*Bb.y)*inv;
    stc(FxH, FxL, ((size_t)(img*3+2)*SP + k)*FH + h, o);
}

// ---------------- output assembly ----------------
__global__ void crop_kernel(const float* __restrict__ sp, float* __restrict__ outp, int total)
{
    int idx = blockIdx.x*256 + threadIdx.x;
    if (idx >= total) return;
    int x = idx & 255; int r = idx >> 8; int y = r & 255; int plane = r >> 8;
    outp[idx] = sp[((size_t)plane*FH + (y+22))*FH + (x+22)];
}

__global__ void kcopy_kernel(const float* __restrict__ kful, float* __restrict__ outp, int total)
{
    int idx = blockIdx.x*256 + threadIdx.x;
    if (idx >= total) return;
    int rem = idx % 2025; int img = idx / 2025;
    int x = rem % 45; int y = rem / 45;
    outp[idx] = kful[(size_t)img*FH*FH + y*FH + x];
}

// =====================================================================
extern "C" void kernel_launch(void* const* d_in, const int* in_sizes, int n_in,
                              void* d_out, int out_size, void* d_ws, size_t ws_size,
                              hipStream_t stream)
{
    (void)in_sizes; (void)n_in; (void)out_size;
    const float* blurred = (const float*)d_in[0];
    const float* w0      = (const float*)d_in[1];
    const float* wsw     = (const float*)d_in[2];
    const float* biases  = (const float*)d_in[3];
    const float* kbias   = (const float*)d_in[4];
    const float* kprox   = (const float*)d_in[5];
    const float* zetas   = (const float*)d_in[6];
    const float* eta     = (const float*)d_in[7];
    float* outp = (float*)d_out;

    auto al = [](size_t b) { return (b + 255) & ~(size_t)255; };
    const size_t SPEC1 = (size_t)16*SP*KP*2;      // one image's 16-plane spectrum, one bf16 half
    const size_t SPECK = (size_t)SP*KP*2;         // kernel spectrum half
    auto need = [&](int G) -> size_t {
        size_t s = 0;
        s += 4*al((size_t)KP*KP*2);               // EfH/L, EiH/L
        s += 2*al((size_t)448*FH*2);              // Tt
        s += 2*al((size_t)FH*416*2);              // Ut
        s += al(432*4);                           // w0c
        s += al((size_t)10*G*16*65536*4);         // fyN
        s += al((size_t)G*16*SPW*4);              // zsp fp32
        s += 2*al((size_t)G*16*SPW*2);            // splitS H/L
        s += 6*al(G*SPEC1);                       // mid, Fz, Ffy H/L
        s += 8*al(G*SPECK);                       // Fk, kfA, kfB, midK H/L
        s += 4*al((size_t)G*3*SP*KP*2);           // FyB, FxB H/L
        s += 2*al((size_t)G*SPW*4);               // kraw, kful
        s += al((size_t)G*64*8) + al(256);        // lseP, kmax
        return s;
    };
    int G = 4;
    while (G > 1 && need(G) > ws_size) G >>= 1;

    char* base = (char*)d_ws;
    size_t off = 0;
    auto alloc = [&](size_t bytes) -> void* {
        void* p = (void*)(base + off);
        off += (bytes + 255) & ~(size_t)255;
        return p;
    };
    u16* EfH = (u16*)alloc((size_t)KP*KP*2);
    u16* EfL = (u16*)alloc((size_t)KP*KP*2);
    u16* EiH = (u16*)alloc((size_t)KP*KP*2);
    u16* EiL = (u16*)alloc((size_t)KP*KP*2);
    u16* TtH = (u16*)alloc((size_t)448*FH*2);
    u16* TtL = (u16*)alloc((size_t)448*FH*2);
    u16* UtH = (u16*)alloc((size_t)FH*416*2);
    u16* UtL = (u16*)alloc((size_t)FH*416*2);
    float* w0cB = (float*)alloc(432*4);
    float* fyN  = (float*)alloc((size_t)10*G*16*65536*4);
    float* zsp  = (float*)alloc((size_t)G*16*SPW*4);
    u16* spSH = (u16*)alloc((size_t)G*16*SPW*2);
    u16* spSL = (u16*)alloc((size_t)G*16*SPW*2);
    u16* midH = (u16*)alloc(G*SPEC1);  u16* midL = (u16*)alloc(G*SPEC1);
    u16* FzH  = (u16*)alloc(G*SPEC1);  u16* FzL  = (u16*)alloc(G*SPEC1);
    u16* FfyH = (u16*)alloc(G*SPEC1);  u16* FfyL = (u16*)alloc(G*SPEC1);
    u16* FkH  = (u16*)alloc(G*SPECK);  u16* FkL  = (u16*)alloc(G*SPECK);
    u16* kfAH = (u16*)alloc(G*SPECK);  u16* kfAL = (u16*)alloc(G*SPECK);
    u16* kfBH = (u16*)alloc(G*SPECK);  u16* kfBL = (u16*)alloc(G*SPECK);
    u16* mKH  = (u16*)alloc(G*SPECK);  u16* mKL  = (u16*)alloc(G*SPECK);
    u16* FyBH = (u16*)alloc((size_t)G*3*SP*KP*2); u16* FyBL = (u16*)alloc((size_t)G*3*SP*KP*2);
    u16* FxBH = (u16*)alloc((size_t)G*3*SP*KP*2); u16* FxBL = (u16*)alloc((size_t)G*3*SP*KP*2);
    float* kraw = (float*)alloc((size_t)G*SPW*4);
    float* kful = (float*)alloc((size_t)G*SPW*4);
    float2* lseP = (float2*)alloc((size_t)G*64*8);
    float*  kmaxB = (float*)alloc(256);
    float2* Fw0B = (float2*)fyN;   // 28.45 MB overlay; fyN dead at final stage

    init_estack<<<(KP*KP+255)/256, 256, 0, stream>>>(EfH, EfL, 0);
    init_estack<<<(KP*KP+255)/256, 256, 0, stream>>>(EiH, EiL, 1);
    init_tt<<<(448*FH+255)/256, 256, 0, stream>>>(TtH, TtL);
    init_ut<<<(FH*416+255)/256, 256, 0, stream>>>(UtH, UtL);
    w0c_kernel<<<1, 64, 0, stream>>>(w0, w0cB);

    auto r2c = [&](const u16* H, const u16* L, int ktlo, int kthi, u16* oH, u16* oL, int B) {
        r2c_mfma<<<dim3(7, 3, B), 256, 0, stream>>>(H, L, ktlo, kthi, TtH, TtL, oH, oL);
    };
    auto zg = [&](const u16* EH, const u16* EL, const u16* SH, const u16* SL,
                  u16* oH, u16* oL, int N) {
        zg_mfma<<<dim3((N+63)/64, 6), 256, 0, stream>>>(EH, EL, SH, SL, oH, oL, N);
    };
    auto c2r = [&](const u16* SH, const u16* SL, float* o, int B,
                   const float* thr, u16* sH, u16* sL) {
        c2r_mfma<<<dim3(6, 3, B), 256, 0, stream>>>(
            (const u32*)SH, (const u32*)SL, UtH, UtL, o, thr, sH, sL);
    };
    auto splitp = [&](const float* src, int inH, int inW, int oY, int oX,
                      const float* thr, int planes) {
        int tot = planes*FH*192;
        split_pad<<<(tot+255)/256, 256, 0, stream>>>(src, inH, inW, oY, oX, thr,
                                                     (u32*)spSH, (u32*)spSL, tot);
    };

    const size_t IMG16 = (size_t)16*65536;
    const size_t LAY   = (size_t)G*IMG16;
    const int N1 = G*16*SP, N2 = G*SP, N3 = G*3*SP;
    const int tot1 = N1*FH, tot2 = N2*FH;

    for (int g0 = 0; g0 < 4; g0 += G) {
        const float* img = blurred + (size_t)g0*3*65536;

        conv3x3_kernel<<<dim3(16,16,G), 256, 0, stream>>>(
            img, w0cB, fyN, 3, 1, (size_t)3*65536, IMG16);
        for (int l = 1; l < 10; ++l)
            conv3x3_kernel<<<dim3(16,16,G), 256, 0, stream>>>(
                fyN + (size_t)(l-1)*LAY, wsw + (size_t)(l-1)*2304,
                fyN + (size_t)l*LAY, 16, 0, IMG16, IMG16);

        // z init: circshift+softt -> split planes -> Fz
        int totZ = G*16*FH*192;
        zinit_split<<<(totZ+255)/256, 256, 0, stream>>>(fyN + 9*LAY, biases,
                                                        (u32*)spSH, (u32*)spSL, totZ);
        r2c(spSH, spSL, 0, FH, midH, midL, G*16);
        zg(EfH, EfL, midH, midL, FzH, FzL, N1);

        zero_kernel<<<(G*SPW+255)/256, 256, 0, stream>>>(kful, G*SPW);
        kdelta_kernel<<<1, 64, 0, stream>>>(kful, G);

        for (int it = 0; it < 10; ++it) {
            int Lfy = 9 - it;
            splitp(fyN + (size_t)Lfy*LAY, 256, 256, 44, 44, nullptr, G*16);
            r2c(spSH, spSL, 32, 320, midH, midL, G*16);
            zg(EfH, EfL, midH, midL, FfyH, FfyL, N1);
            splitp(kful, FH, FH, 0, 0, nullptr, G);
            r2c(spSH, spSL, 0, FH, mKH, mKL, G);
            zg(EfH, EfL, mKH, mKL, FkH, FkL, N2);
            fg_kernel<<<(tot1+255)/256, 256, 0, stream>>>(
                (u32*)FfyH, (u32*)FfyL, (u32*)FzH, (u32*)FzL,
                (u32*)FkH, (u32*)FkL, zetas, it, tot1);
            zg(EiH, EiL, FzH, FzL, midH, midL, N1);
            c2r(midH, midL, zsp, G*16, biases + (it+1)*16, spSH, spSL);  // zsp + softt-split
            r2c(spSH, spSL, 0, FH, midH, midL, G*16);
            zg(EfH, EfL, midH, midL, FzH, FzL, N1);                      // Fz_new
            knum_kernel<<<(tot2+255)/256, 256, 0, stream>>>(
                (u32*)FzH, (u32*)FzL, (u32*)FfyH, (u32*)FfyL,
                (u32*)FkH, (u32*)FkL, kprox, it, tot2, (u32*)kfAH, (u32*)kfAL);
            zg(EiH, EiL, kfAH, kfAL, kfBH, kfBL, N2);
            c2r(kfBH, kfBL, kraw, G, nullptr, nullptr, nullptr);
            lse_part_kernel<<<dim3(64,G), 256, 0, stream>>>(kraw, lseP);
            lse_final_kernel<<<G, 64, 0, stream>>>(lseP, kmaxB);
            knew_kernel<<<G, 256, 0, stream>>>(kraw, kmaxB, kbias, it, kful);
        }

        // ---- final stage ----
        splitp(img, 256, 256, 44, 44, nullptr, 3*G);
        r2c(spSH, spSL, 32, 320, midH, midL, 3*G);
        zg(EfH, EfL, midH, midL, FyBH, FyBL, N3);
        splitp(kful, FH, FH, 0, 0, nullptr, G);
        r2c(spSH, spSL, 0, FH, mKH, mKL, G);
        zg(EfH, EfL, mKH, mKL, FkH, FkL, N2);
        splitp(zsp, FH, FH, 0, 0, biases + 11*16, G*16);   // softt(b_final) on last zsp
        r2c(spSH, spSL, 0, FH, midH, midL, G*16);
        zg(EfH, EfL, midH, midL, FzH, FzL, N1);            // Fg2
        fw0_kernel<<<(48*FH*KF+255)/256, 256, 0, stream>>>(w0cB, Fw0B);
        wiener_kernel<<<(tot2+255)/256, 256, 0, stream>>>(
            (u32*)FkH, (u32*)FkL, (u32*)FyBH, (u32*)FyBL, Fw0B,
            (u32*)FzH, (u32*)FzL, eta, tot2, (u32*)FxBH, (u32*)FxBL);
        zg(EiH, EiL, FxBH, FxBL, midH, midL, N3);
        c2r(midH, midL, zsp, 3*G, nullptr, nullptr, nullptr);
        int totC = G*3*65536;
        crop_kernel<<<(totC+255)/256, 256, 0, stream>>>(zsp, outp + (size_t)g0*3*65536, totC);
        int totKC = G*2025;
        kcopy_kernel<<<(totKC+255)/256, 256, 0, stream>>>(kful, outp + 786432 + g0*2025, totKC);
    }
}